// Round 13
// baseline (111.267 us; speedup 1.0000x reference)
//
#include <hip/hip_runtime.h>
#include <math.h>

#define BB 8
#define SS 2048
#define DD 1024
// Pipeline (FFT order swapped; 2D FFT is separable):
//   K_A (k_fft_sx): per 4 d-columns: exp -> in-block softmax sum -> scale ->
//                   visual write + 2x complex FFT-2048 (2 real cols packed per FFT)
//                   -> unpack half-spectrum -> E1[b][k][d] (row-major, 64 MB)
//                   E1 row 0 packs (A[0], A[1024]) per column.
//   K_B (k_fft_dd): per spectral row k1: complex FFT-1024 along D -> write own row k1
//                   and Hermitian mirror row S-k1 (reversed) as FULL contiguous rows.
//                   Row 0 (packed) -> Zrow scratch -> same-block tail writes rows 0,1024.

typedef float nf2 __attribute__((ext_vector_type(2)));   // native vec2 for nontemporal builtins

__device__ __forceinline__ float2 ntload2(const float2* p) {
    nf2 v = __builtin_nontemporal_load((const nf2*)p);
    return make_float2(v.x, v.y);
}

__device__ __forceinline__ float2 cmul(float2 a, float2 b) {
    return make_float2(fmaf(a.x, b.x, -a.y * b.y), fmaf(a.x, b.y, a.y * b.x));
}
__device__ __forceinline__ float2 c_add(float2 a, float2 b){ return make_float2(a.x+b.x, a.y+b.y); }
__device__ __forceinline__ float2 c_sub(float2 a, float2 b){ return make_float2(a.x-b.x, a.y-b.y); }
__device__ __forceinline__ float2 c_mi(float2 a){ return make_float2(a.y, -a.x); }   // -i*a

// DFT-4: X[k] = sum_q x_q (-i)^{qk}
__device__ __forceinline__ void dft4(float2 c0, float2 c1, float2 c2, float2 c3,
                                     float2& o0, float2& o1, float2& o2, float2& o3) {
    float2 d0 = c_add(c0, c2), d1 = c_sub(c0, c2);
    float2 d2 = c_add(c1, c3), d3 = c_mi(c_sub(c1, c3));
    o0 = c_add(d0, d2); o1 = c_add(d1, d3); o2 = c_sub(d0, d2); o3 = c_sub(d1, d3);
}

// in-register DFT-16 (natural order in/out); twiddles are compile-time constants
__device__ __forceinline__ void dft16(float2* z) {
    float2 a[16];
    #pragma unroll
    for (int r0 = 0; r0 < 4; ++r0)
        dft4(z[r0], z[r0+4], z[r0+8], z[r0+12], a[4*r0], a[4*r0+1], a[4*r0+2], a[4*r0+3]);
    const float2 W1 = {0.9238795325f, -0.3826834324f};
    const float2 W2 = {0.7071067812f, -0.7071067812f};
    const float2 W3 = {0.3826834324f, -0.9238795325f};
    const float2 W6 = {-0.7071067812f, -0.7071067812f};
    const float2 W9 = {-0.9238795325f, 0.3826834324f};
    a[5]  = cmul(a[5],  W1); a[6]  = cmul(a[6],  W2); a[7]  = cmul(a[7],  W3);
    a[9]  = cmul(a[9],  W2); a[10] = c_mi(a[10]);     a[11] = cmul(a[11], W6);
    a[13] = cmul(a[13], W3); a[14] = cmul(a[14], W6); a[15] = cmul(a[15], W9);
    #pragma unroll
    for (int m = 0; m < 4; ++m)
        dft4(a[m], a[4+m], a[8+m], a[12+m], z[m], z[m+4], z[m+8], z[m+12]);
}

// in-register DFT-8 (natural order)
__device__ __forceinline__ void dft8(const float2* u, float2* X) {
    float2 A0,A1,A2,A3,B0,B1,B2,B3;
    dft4(u[0], u[2], u[4], u[6], A0, A1, A2, A3);
    dft4(u[1], u[3], u[5], u[7], B0, B1, B2, B3);
    const float r = 0.7071067812f;
    float2 W1B = make_float2(r*(B1.x + B1.y), r*(B1.y - B1.x));   // (r,-r)*B1
    float2 W2B = c_mi(B2);
    float2 W3B = make_float2(r*(B3.y - B3.x), -r*(B3.x + B3.y));  // (-r,-r)*B3
    X[0] = c_add(A0, B0);  X[4] = c_sub(A0, B0);
    X[1] = c_add(A1, W1B); X[5] = c_sub(A1, W1B);
    X[2] = c_add(A2, W2B); X[6] = c_sub(A2, W2B);
    X[3] = c_add(A3, W3B); X[7] = c_sub(A3, W3B);
}

// ---------------- K_A: softmax + 2048-pt FFT along S for 4 columns ----------------
// 256 threads, LDS 35.7 KB -> 4 blocks/CU (16 waves). Grid 2048 = 2 clean rounds.
#define CS1 2072   // layout-1 column stride (float2)
#define CS2 2232   // layout-2 column stride (float2)
__global__ __launch_bounds__(256, 4) void k_fft_sx(const float* __restrict__ x,
                                                   float* __restrict__ visual,
                                                   float2* __restrict__ E1) {
    __shared__ float2 buf[2 * CS2];        // 35,712 B
    __shared__ float2 ssum[8];             // 4 waves x 2 column-pairs
    __shared__ float2 wcol[2];
    const int t = threadIdx.x;             // 0..255
    // XCD swizzle: same-b blocks -> same XCD; 4 G-blocks sharing a 64B x-line co-resident
    const int b = blockIdx.x & 7;
    const int G = blockIdx.x >> 3;         // 0..255 ; d-columns 4G..4G+3
    const int c = t & 1;                   // column-PAIR (d = 4G+2c, 4G+2c+1)
    const int q = t >> 1;                  // 0..127

    float2 z[16];
    // ---- load x pairs + exp ----
    {
        const float* xb = x + (size_t)b * SS * DD + 4 * G + 2 * c;
        #pragma unroll
        for (int r = 0; r < 16; ++r) {
            nf2 v = __builtin_nontemporal_load((const nf2*)(xb + (size_t)(q + 128 * r) * DD));
            z[r] = make_float2(__expf(v.x), __expf(v.y));
        }
    }
    // ---- column-pair sums: thread partial -> wave shuffle -> LDS -> w ----
    {
        float2 ps = make_float2(0.f, 0.f);
        #pragma unroll
        for (int r = 0; r < 16; ++r) { ps.x += z[r].x; ps.y += z[r].y; }
        #pragma unroll
        for (int m = 2; m < 64; m <<= 1) {   // xor over lane bits 1..5 keeps c (bit 0)
            ps.x += __shfl_xor(ps.x, m, 64);
            ps.y += __shfl_xor(ps.y, m, 64);
        }
        if ((t & 63) < 2) ssum[(t >> 6) * 2 + (t & 1)] = ps;
    }
    __syncthreads();
    if (t < 2) {
        float2 s = make_float2(0.f, 0.f);
        #pragma unroll
        for (int w = 0; w < 4; ++w) { s.x += ssum[w * 2 + t].x; s.y += ssum[w * 2 + t].y; }
        wcol[t] = make_float2(1.f / s.x, 1.f / s.y);
    }
    __syncthreads();
    // ---- scale by softmax weight; write visual from the same registers ----
    {
        const float2 wgt = wcol[c];
        float* vb = visual + (size_t)b * SS * DD + 4 * G + 2 * c;
        #pragma unroll
        for (int r = 0; r < 16; ++r) {
            z[r].x *= wgt.x; z[r].y *= wgt.y;
            *(float2*)(vb + (size_t)(q + 128 * r) * DD) = z[r];   // 8B; 2 lanes -> 16B chunk
        }
    }
    // ---- level 1: DFT-16 over r, twiddle W2048^{q k1} ----
    {
        dft16(z);
        float sn, cs;
        __sincosf(-6.283185307179586f * (float)q / 2048.f, &sn, &cs);
        float2 w = make_float2(cs, sn), wk = w;
        #pragma unroll
        for (int k1 = 1; k1 < 16; ++k1) { z[k1] = cmul(z[k1], wk); wk = cmul(wk, w); }
        float2* p = buf + c * CS1 + q;     // layout1: c*CS1 + 129*k1 + q
        #pragma unroll
        for (int k1 = 0; k1 < 16; ++k1) p[129 * k1] = z[k1];
    }
    __syncthreads();
    // ---- level 2: DFT-16 over q2 (q = q1 + 8 q2) ----
    {
        const int k1 = t & 15, cc = (t >> 4) & 1, q1 = t >> 5;   // q1 0..7
        const float2* p = buf + cc * CS1 + 129 * k1 + q1;
        #pragma unroll
        for (int j = 0; j < 16; ++j) z[j] = p[8 * j];
        __syncthreads();                   // all layout1 reads done before layout2 writes
        dft16(z);
        float sn, cs;
        __sincosf(-6.283185307179586f * (float)q1 / 128.f, &sn, &cs);
        float2 w = make_float2(cs, sn), wk = w;
        #pragma unroll
        for (int a = 1; a < 16; ++a) { z[a] = cmul(z[a], wk); wk = cmul(wk, w); }
        float2* p2 = buf + cc * CS2 + 280 * q1 + 17 * k1;   // layout2
        #pragma unroll
        for (int a = 0; a < 16; ++a) p2[a] = z[a];
    }
    __syncthreads();
    // ---- level 3: DFT-8 over q1 -> Z in registers (both e) ----
    const int rest = t >> 1;
    const int k1 = rest & 15, k2h = rest >> 4;      // k2h 0..7
    float2 Xa[8], Xb[8];
    {
        float2 u[8];
        const float2* p = buf + c * CS2 + 17 * k1 + 2 * k2h;   // k2a = 2k2h
        #pragma unroll
        for (int q1 = 0; q1 < 8; ++q1) u[q1] = p[280 * q1];
        dft8(u, Xa);
        #pragma unroll
        for (int q1 = 0; q1 < 8; ++q1) u[q1] = p[280 * q1 + 1]; // k2a = 2k2h+1
        dft8(u, Xb);
    }
    __syncthreads();                       // all layout2 reads done before Z overwrite
    // ---- Z -> LDS linear by true frequency k ----
    float2* Zc = buf + c * CS2;
    #pragma unroll
    for (int k2b = 0; k2b < 8; ++k2b) {
        Zc[k1 + 32 * k2h + 256 * k2b]      = Xa[k2b];   // k = k1+16*(2k2h)+256*k2b
        Zc[k1 + 32 * k2h + 16 + 256 * k2b] = Xb[k2b];   // k = k1+16*(2k2h+1)+256*k2b
    }
    __syncthreads();
    // ---- unpack real-pair spectra and store E1 (k = 0..1023) ----
    // A[k]=(Z[k]+conj(Zm))/2 (col d=4G+2c), B[k]=-i(Z[k]-conj(Zm))/2 (col d=4G+2c+1)
    {
        #pragma unroll
        for (int e = 0; e < 2; ++e) {
            #pragma unroll
            for (int k2b = 0; k2b < 4; ++k2b) {        // k < 1024 only
                const int k = k1 + 16 * (2 * k2h + e) + 256 * k2b;
                float2 Z  = Zc[k];
                float2 Zm = Zc[(2048 - k) & 2047];
                float2 A = make_float2(0.5f * (Z.x + Zm.x), 0.5f * (Z.y - Zm.y));
                float2 B = make_float2(0.5f * (Z.y + Zm.y), 0.5f * (Zm.x - Z.x));
                if (k == 0) {              // pack (A[0], A[1024]) / (B[0], B[1024]) — all real
                    float2 Zh = Zc[1024];
                    A = make_float2(A.x, Zh.x);
                    B = make_float2(B.x, Zh.y);
                }
                // 16B store; lanes c=0..1 -> 32B contiguous chunk per k
                *(float4*)(E1 + ((size_t)b * 1024 + k) * 1024 + 4 * G + 2 * c)
                    = make_float4(A.x, A.y, B.x, B.y);
            }
        }
    }
}

// ---------------- K_B: 1024-pt FFT along D per spectral row; full-row writes ----------------
#define RB 1040   // per-row LDS stride (float2): 16*65
__global__ __launch_bounds__(256, 4) void k_fft_dd(const float2* __restrict__ E1,
                                                   float* __restrict__ out,
                                                   float2* __restrict__ Zrow) {
    __shared__ float2 buf[4 * RB];         // 33,280 B -> 4 blocks/CU
    const int t = threadIdx.x;
    const int row = t >> 6;                // 0..3
    const int tr  = t & 63;
    const int b   = blockIdx.x >> 8;
    const int rg  = blockIdx.x & 255;
    const int kr  = 4 * rg + row;          // spectral row 0..1023 (row 0 packed)
    float2* rbuf = buf + row * RB;

    float2 z[16];
    // ---- level 1: load complex row + DFT-16 over r (d = tr + 64 r) ----
    {
        const float2* er = E1 + ((size_t)b * 1024 + kr) * 1024;
        #pragma unroll
        for (int r = 0; r < 16; ++r) z[r] = ntload2(er + tr + 64 * r);
        dft16(z);
        float sn, cs;                       // *= W1024^{tr * f}
        __sincosf(-6.283185307179586f * (float)tr / 1024.f, &sn, &cs);
        float2 w = make_float2(cs, sn), wk = w;
        #pragma unroll
        for (int f = 1; f < 16; ++f) { z[f] = cmul(z[f], wk); wk = cmul(wk, w); }
        #pragma unroll
        for (int f = 0; f < 16; ++f) rbuf[65 * f + tr] = z[f];
    }
    __syncthreads();
    // ---- level 2: DFT-16 over q2 (q = q1 + 4 q2), twiddle W64^{q1 a} ----
    {
        const int f = tr & 15, q1 = tr >> 4;       // q1 0..3
        const float2* p = rbuf + 65 * f + q1;
        #pragma unroll
        for (int j = 0; j < 16; ++j) z[j] = p[4 * j];
        __syncthreads();
        dft16(z);
        float sn, cs;
        __sincosf(-6.283185307179586f * (float)q1 / 64.f, &sn, &cs);
        float2 w = make_float2(cs, sn), wk = w;
        #pragma unroll
        for (int a = 1; a < 16; ++a) { z[a] = cmul(z[a], wk); wk = cmul(wk, w); }
        float2* p2 = rbuf + 65 * f + 16 * q1;
        #pragma unroll
        for (int a = 0; a < 16; ++a) p2[a] = z[a];
    }
    __syncthreads();
    // ---- level 3: DFT-4 over q1; write own row kr + mirror row SS-kr ----
    {
        const int f = tr & 15, j = tr >> 4;
        float* orow = out + ((size_t)b * SS + kr) * DD;
        float* mrow = out + ((size_t)b * SS + ((SS - kr) & (SS - 1))) * DD;
        float2* Zr = Zrow + b * DD;
        const bool pk = (kr == 0);
        #pragma unroll
        for (int jj = 0; jj < 4; ++jj) {
            const int k2a = 4 * j + jj;
            const float2* p = rbuf + 65 * f + k2a;
            float2 X0, X1, X2, X3;
            dft4(p[0], p[16], p[32], p[48], X0, X1, X2, X3);   // over q1 (stride 16)
            const int kb = f + 16 * k2a;           // k2 = kb + 256*m
            if (pk) {
                Zr[kb] = X0; Zr[kb+256] = X1; Zr[kb+512] = X2; Zr[kb+768] = X3;
            } else {
                __builtin_nontemporal_store(X0.x, orow + kb);          // 64B chunks, nt-safe
                __builtin_nontemporal_store(X1.x, orow + kb + 256);
                __builtin_nontemporal_store(X2.x, orow + kb + 512);
                __builtin_nontemporal_store(X3.x, orow + kb + 768);
                mrow[(DD - kb)       & (DD - 1)] = X0.x;   // cached: reversed chunks merge in L2
                mrow[(DD - kb - 256) & (DD - 1)] = X1.x;
                mrow[(DD - kb - 512) & (DD - 1)] = X2.x;
                mrow[(DD - kb - 768) & (DD - 1)] = X3.x;
            }
        }
    }
    // ---- tail (rg==0 only): unpack packed row -> out rows 0 and 1024 ----
    // Zr written entirely by THIS block; __syncthreads drains vmcnt (proven pattern).
    if (rg == 0) {
        __syncthreads();
        const float2* Zr = Zrow + b * DD;
        float* r0 = out + (size_t)b * SS * DD;
        float* r1 = out + ((size_t)b * SS + 1024) * DD;
        #pragma unroll
        for (int i = 0; i < 4; ++i) {
            const int k2 = t + (i << 8);           // 0..1023
            const int km = (DD - k2) & (DD - 1);
            float2 Zk = Zr[k2], Zm = Zr[km];
            r0[k2] = 0.5f * (Zk.x + Zm.x);         // Re row 0
            r1[k2] = 0.5f * (Zk.y + Zm.y);         // Re row 1024
        }
    }
}

extern "C" void kernel_launch(void* const* d_in, const int* in_sizes, int n_in,
                              void* d_out, int out_size, void* d_ws, size_t ws_size,
                              hipStream_t stream) {
    const float* x = (const float*)d_in[0];
    float* out    = (float*)d_out;                        // Re(FFT2) : 16,777,216 floats
    float* visual = out + (size_t)BB * SS * DD;           // softmax  : 16,777,216 floats

    char* ws = (char*)d_ws;
    float2* E1   = (float2*)ws;                                  // 64 MiB: [b][k][d]
    float2* Zrow = (float2*)(ws + (size_t)BB * 1024 * 1024 * sizeof(float2));  // 64 KiB

    hipLaunchKernelGGL(k_fft_sx, dim3(BB * 256), dim3(256), 0, stream, x, visual, E1);
    hipLaunchKernelGGL(k_fft_dd, dim3(BB * 256), dim3(256), 0, stream, E1, out, Zrow);
}

// Round 14
// 79.742 us; speedup vs baseline: 1.3953x; 1.3953x over previous
//
#include <hip/hip_runtime.h>
#include <math.h>

#define BB 8
#define SS 2048
#define DD 1024
// Pipeline (separable 2D FFT, S-axis first):
//   K_A (k_fft_sx): per 16 d-columns (8 pairs): exp -> in-block softmax sum -> scale ->
//                   visual write + 8x complex FFT-2048 (2 real cols packed per FFT)
//                   -> unpack half-spectrum -> E1[b][k][d] (row-major, 64 MB)
//                   E1 row 0 packs (A[0], A[1024]) per column. All global accesses
//                   are full 64B lines (R13 lesson: chunk width, not block count).
//   K_B (k_fft_dd): per spectral row k1: complex FFT-1024 along D -> write own row k1
//                   and Hermitian mirror row S-k1 (reversed) as FULL contiguous rows.
//                   Row 0 (packed) -> Zrow scratch -> same-block tail writes rows 0,1024.

typedef float nf2 __attribute__((ext_vector_type(2)));   // native vec2 for nontemporal builtins

__device__ __forceinline__ float2 ntload2(const float2* p) {
    nf2 v = __builtin_nontemporal_load((const nf2*)p);
    return make_float2(v.x, v.y);
}

__device__ __forceinline__ float2 cmul(float2 a, float2 b) {
    return make_float2(fmaf(a.x, b.x, -a.y * b.y), fmaf(a.x, b.y, a.y * b.x));
}
__device__ __forceinline__ float2 c_add(float2 a, float2 b){ return make_float2(a.x+b.x, a.y+b.y); }
__device__ __forceinline__ float2 c_sub(float2 a, float2 b){ return make_float2(a.x-b.x, a.y-b.y); }
__device__ __forceinline__ float2 c_mi(float2 a){ return make_float2(a.y, -a.x); }   // -i*a

// DFT-4: X[k] = sum_q x_q (-i)^{qk}
__device__ __forceinline__ void dft4(float2 c0, float2 c1, float2 c2, float2 c3,
                                     float2& o0, float2& o1, float2& o2, float2& o3) {
    float2 d0 = c_add(c0, c2), d1 = c_sub(c0, c2);
    float2 d2 = c_add(c1, c3), d3 = c_mi(c_sub(c1, c3));
    o0 = c_add(d0, d2); o1 = c_add(d1, d3); o2 = c_sub(d0, d2); o3 = c_sub(d1, d3);
}

// in-register DFT-16 (natural order in/out); twiddles are compile-time constants
__device__ __forceinline__ void dft16(float2* z) {
    float2 a[16];
    #pragma unroll
    for (int r0 = 0; r0 < 4; ++r0)
        dft4(z[r0], z[r0+4], z[r0+8], z[r0+12], a[4*r0], a[4*r0+1], a[4*r0+2], a[4*r0+3]);
    const float2 W1 = {0.9238795325f, -0.3826834324f};
    const float2 W2 = {0.7071067812f, -0.7071067812f};
    const float2 W3 = {0.3826834324f, -0.9238795325f};
    const float2 W6 = {-0.7071067812f, -0.7071067812f};
    const float2 W9 = {-0.9238795325f, 0.3826834324f};
    a[5]  = cmul(a[5],  W1); a[6]  = cmul(a[6],  W2); a[7]  = cmul(a[7],  W3);
    a[9]  = cmul(a[9],  W2); a[10] = c_mi(a[10]);     a[11] = cmul(a[11], W6);
    a[13] = cmul(a[13], W3); a[14] = cmul(a[14], W6); a[15] = cmul(a[15], W9);
    #pragma unroll
    for (int m = 0; m < 4; ++m)
        dft4(a[m], a[4+m], a[8+m], a[12+m], z[m], z[m+4], z[m+8], z[m+12]);
}

// in-register DFT-8 (natural order)
__device__ __forceinline__ void dft8(const float2* u, float2* X) {
    float2 A0,A1,A2,A3,B0,B1,B2,B3;
    dft4(u[0], u[2], u[4], u[6], A0, A1, A2, A3);
    dft4(u[1], u[3], u[5], u[7], B0, B1, B2, B3);
    const float r = 0.7071067812f;
    float2 W1B = make_float2(r*(B1.x + B1.y), r*(B1.y - B1.x));   // (r,-r)*B1
    float2 W2B = c_mi(B2);
    float2 W3B = make_float2(r*(B3.y - B3.x), -r*(B3.x + B3.y));  // (-r,-r)*B3
    X[0] = c_add(A0, B0);  X[4] = c_sub(A0, B0);
    X[1] = c_add(A1, W1B); X[5] = c_sub(A1, W1B);
    X[2] = c_add(A2, W2B); X[6] = c_sub(A2, W2B);
    X[3] = c_add(A3, W3B); X[7] = c_sub(A3, W3B);
}

// ---------------- K_A: softmax + 2048-pt FFT along S for 16 columns ----------------
// 1024 threads, LDS ~144 KB (1 block/CU, 16 waves). Grid 512 = 2 clean rounds.
#define CS1 2072   // layout-1 column-pair stride (float2)
#define CS2 2232   // layout-2 column-pair stride (float2)
__global__ __launch_bounds__(1024, 4) void k_fft_sx(const float* __restrict__ x,
                                                    float* __restrict__ visual,
                                                    float2* __restrict__ E1) {
    __shared__ float2 buf[8 * CS2];        // 142,848 B
    __shared__ float2 ssum[128];           // 16 waves x 8 column-pairs
    __shared__ float2 wcol[8];
    const int t = threadIdx.x;             // 0..1023
    const int b = blockIdx.x & 7;          // XCD swizzle: same-b blocks -> same XCD
    const int G = blockIdx.x >> 3;         // 0..63 ; d-columns 16G..16G+15
    const int c = t & 7;                   // column-PAIR (d = 16G+2c, 16G+2c+1)
    const int q = t >> 3;                  // 0..127

    float2 z[16];
    // ---- load x pairs + exp (8 lanes x 8B = full 64B line per row) ----
    {
        const float* xb = x + (size_t)b * SS * DD + 16 * G + 2 * c;
        #pragma unroll
        for (int r = 0; r < 16; ++r) {
            nf2 v = __builtin_nontemporal_load((const nf2*)(xb + (size_t)(q + 128 * r) * DD));
            z[r] = make_float2(__expf(v.x), __expf(v.y));
        }
    }
    // ---- column-pair sums: thread partial -> wave shuffle -> LDS -> w ----
    {
        float2 ps = make_float2(0.f, 0.f);
        #pragma unroll
        for (int r = 0; r < 16; ++r) { ps.x += z[r].x; ps.y += z[r].y; }
        #pragma unroll
        for (int m = 8; m < 64; m <<= 1) {   // xor over lane bits 3..5 keeps c (bits 0-2)
            ps.x += __shfl_xor(ps.x, m, 64);
            ps.y += __shfl_xor(ps.y, m, 64);
        }
        if ((t & 63) < 8) ssum[(t >> 6) * 8 + (t & 7)] = ps;
    }
    __syncthreads();
    if (t < 8) {
        float2 s = make_float2(0.f, 0.f);
        #pragma unroll
        for (int w = 0; w < 16; ++w) { s.x += ssum[w * 8 + t].x; s.y += ssum[w * 8 + t].y; }
        wcol[t] = make_float2(1.f / s.x, 1.f / s.y);
    }
    __syncthreads();
    // ---- scale by softmax weight; write visual (full 64B lines) ----
    {
        const float2 wgt = wcol[c];
        float* vb = visual + (size_t)b * SS * DD + 16 * G + 2 * c;
        #pragma unroll
        for (int r = 0; r < 16; ++r) {
            z[r].x *= wgt.x; z[r].y *= wgt.y;
            *(float2*)(vb + (size_t)(q + 128 * r) * DD) = z[r];
        }
    }
    // ---- level 1: DFT-16 over r, twiddle W2048^{q k1} ----
    {
        dft16(z);
        float sn, cs;
        __sincosf(-6.283185307179586f * (float)q / 2048.f, &sn, &cs);
        float2 w = make_float2(cs, sn), wk = w;
        #pragma unroll
        for (int k1 = 1; k1 < 16; ++k1) { z[k1] = cmul(z[k1], wk); wk = cmul(wk, w); }
        float2* p = buf + c * CS1 + q;     // layout1: c*CS1 + 129*k1 + q
        #pragma unroll
        for (int k1 = 0; k1 < 16; ++k1) p[129 * k1] = z[k1];
    }
    __syncthreads();
    // ---- level 2: DFT-16 over q2 (q = q1 + 8 q2) ----
    {
        const int k1 = t & 15, cc = (t >> 4) & 7, q1 = t >> 7;   // q1 0..7
        const float2* p = buf + cc * CS1 + 129 * k1 + q1;
        #pragma unroll
        for (int j = 0; j < 16; ++j) z[j] = p[8 * j];
        __syncthreads();                   // all layout1 reads done before layout2 writes
        dft16(z);
        float sn, cs;
        __sincosf(-6.283185307179586f * (float)q1 / 128.f, &sn, &cs);
        float2 w = make_float2(cs, sn), wk = w;
        #pragma unroll
        for (int a = 1; a < 16; ++a) { z[a] = cmul(z[a], wk); wk = cmul(wk, w); }
        float2* p2 = buf + cc * CS2 + 280 * q1 + 17 * k1;   // layout2
        #pragma unroll
        for (int a = 0; a < 16; ++a) p2[a] = z[a];
    }
    __syncthreads();
    // ---- level 3: DFT-8 over q1 -> Z in registers (both e) ----
    const int rest = t >> 3;
    const int k1 = rest & 15, k2h = rest >> 4;      // k2h 0..7
    float2 Xa[8], Xb[8];
    {
        float2 u[8];
        const float2* p = buf + c * CS2 + 17 * k1 + 2 * k2h;   // k2a = 2k2h
        #pragma unroll
        for (int q1 = 0; q1 < 8; ++q1) u[q1] = p[280 * q1];
        dft8(u, Xa);
        #pragma unroll
        for (int q1 = 0; q1 < 8; ++q1) u[q1] = p[280 * q1 + 1]; // k2a = 2k2h+1
        dft8(u, Xb);
    }
    __syncthreads();                       // all layout2 reads done before Z overwrite
    // ---- Z -> LDS linear by true frequency k ----
    float2* Zc = buf + c * CS2;
    #pragma unroll
    for (int k2b = 0; k2b < 8; ++k2b) {
        Zc[k1 + 32 * k2h + 256 * k2b]      = Xa[k2b];   // k = k1+16*(2k2h)+256*k2b
        Zc[k1 + 32 * k2h + 16 + 256 * k2b] = Xb[k2b];   // k = k1+16*(2k2h+1)+256*k2b
    }
    __syncthreads();
    // ---- unpack real-pair spectra and store E1 (k = 0..1023) ----
    // A[k]=(Z[k]+conj(Zm))/2 (col d=16G+2c), B[k]=-i(Z[k]-conj(Zm))/2 (col d=16G+2c+1)
    {
        #pragma unroll
        for (int e = 0; e < 2; ++e) {
            #pragma unroll
            for (int k2b = 0; k2b < 4; ++k2b) {        // k < 1024 only
                const int k = k1 + 16 * (2 * k2h + e) + 256 * k2b;
                float2 Z  = Zc[k];
                float2 Zm = Zc[(2048 - k) & 2047];
                float2 A = make_float2(0.5f * (Z.x + Zm.x), 0.5f * (Z.y - Zm.y));
                float2 B = make_float2(0.5f * (Z.y + Zm.y), 0.5f * (Zm.x - Z.x));
                if (k == 0) {              // pack (A[0], A[1024]) / (B[0], B[1024]) — all real
                    float2 Zh = Zc[1024];
                    A = make_float2(A.x, Zh.x);
                    B = make_float2(B.x, Zh.y);
                }
                // 16B store; lanes c=0..7 -> 128B contiguous per k
                *(float4*)(E1 + ((size_t)b * 1024 + k) * 1024 + 16 * G + 2 * c)
                    = make_float4(A.x, A.y, B.x, B.y);
            }
        }
    }
}

// ---------------- K_B: 1024-pt FFT along D per spectral row; full-row writes ----------------
#define RB 1040   // per-row LDS stride (float2): 16*65
__global__ __launch_bounds__(256, 4) void k_fft_dd(const float2* __restrict__ E1,
                                                   float* __restrict__ out,
                                                   float2* __restrict__ Zrow) {
    __shared__ float2 buf[4 * RB];         // 33,280 B -> 4 blocks/CU
    const int t = threadIdx.x;
    const int row = t >> 6;                // 0..3
    const int tr  = t & 63;
    const int b   = blockIdx.x >> 8;
    const int rg  = blockIdx.x & 255;
    const int kr  = 4 * rg + row;          // spectral row 0..1023 (row 0 packed)
    float2* rbuf = buf + row * RB;

    float2 z[16];
    // ---- level 1: load complex row + DFT-16 over r (d = tr + 64 r) ----
    {
        const float2* er = E1 + ((size_t)b * 1024 + kr) * 1024;
        #pragma unroll
        for (int r = 0; r < 16; ++r) z[r] = ntload2(er + tr + 64 * r);
        dft16(z);
        float sn, cs;                       // *= W1024^{tr * f}
        __sincosf(-6.283185307179586f * (float)tr / 1024.f, &sn, &cs);
        float2 w = make_float2(cs, sn), wk = w;
        #pragma unroll
        for (int f = 1; f < 16; ++f) { z[f] = cmul(z[f], wk); wk = cmul(wk, w); }
        #pragma unroll
        for (int f = 0; f < 16; ++f) rbuf[65 * f + tr] = z[f];
    }
    __syncthreads();
    // ---- level 2: DFT-16 over q2 (q = q1 + 4 q2), twiddle W64^{q1 a} ----
    {
        const int f = tr & 15, q1 = tr >> 4;       // q1 0..3
        const float2* p = rbuf + 65 * f + q1;
        #pragma unroll
        for (int j = 0; j < 16; ++j) z[j] = p[4 * j];
        __syncthreads();
        dft16(z);
        float sn, cs;
        __sincosf(-6.283185307179586f * (float)q1 / 64.f, &sn, &cs);
        float2 w = make_float2(cs, sn), wk = w;
        #pragma unroll
        for (int a = 1; a < 16; ++a) { z[a] = cmul(z[a], wk); wk = cmul(wk, w); }
        float2* p2 = rbuf + 65 * f + 16 * q1;
        #pragma unroll
        for (int a = 0; a < 16; ++a) p2[a] = z[a];
    }
    __syncthreads();
    // ---- level 3: DFT-4 over q1; write own row kr + mirror row SS-kr ----
    {
        const int f = tr & 15, j = tr >> 4;
        float* orow = out + ((size_t)b * SS + kr) * DD;
        float* mrow = out + ((size_t)b * SS + ((SS - kr) & (SS - 1))) * DD;
        float2* Zr = Zrow + b * DD;
        const bool pk = (kr == 0);
        #pragma unroll
        for (int jj = 0; jj < 4; ++jj) {
            const int k2a = 4 * j + jj;
            const float2* p = rbuf + 65 * f + k2a;
            float2 X0, X1, X2, X3;
            dft4(p[0], p[16], p[32], p[48], X0, X1, X2, X3);   // over q1 (stride 16)
            const int kb = f + 16 * k2a;           // k2 = kb + 256*m
            if (pk) {
                Zr[kb] = X0; Zr[kb+256] = X1; Zr[kb+512] = X2; Zr[kb+768] = X3;
            } else {
                __builtin_nontemporal_store(X0.x, orow + kb);          // 64B chunks, nt-safe
                __builtin_nontemporal_store(X1.x, orow + kb + 256);
                __builtin_nontemporal_store(X2.x, orow + kb + 512);
                __builtin_nontemporal_store(X3.x, orow + kb + 768);
                mrow[(DD - kb)       & (DD - 1)] = X0.x;   // cached: reversed chunks merge in L2
                mrow[(DD - kb - 256) & (DD - 1)] = X1.x;
                mrow[(DD - kb - 512) & (DD - 1)] = X2.x;
                mrow[(DD - kb - 768) & (DD - 1)] = X3.x;
            }
        }
    }
    // ---- tail (rg==0 only): unpack packed row -> out rows 0 and 1024 ----
    // Zr written entirely by THIS block; __syncthreads drains vmcnt (proven pattern).
    if (rg == 0) {
        __syncthreads();
        const float2* Zr = Zrow + b * DD;
        float* r0 = out + (size_t)b * SS * DD;
        float* r1 = out + ((size_t)b * SS + 1024) * DD;
        #pragma unroll
        for (int i = 0; i < 4; ++i) {
            const int k2 = t + (i << 8);           // 0..1023
            const int km = (DD - k2) & (DD - 1);
            float2 Zk = Zr[k2], Zm = Zr[km];
            r0[k2] = 0.5f * (Zk.x + Zm.x);         // Re row 0
            r1[k2] = 0.5f * (Zk.y + Zm.y);         // Re row 1024
        }
    }
}

extern "C" void kernel_launch(void* const* d_in, const int* in_sizes, int n_in,
                              void* d_out, int out_size, void* d_ws, size_t ws_size,
                              hipStream_t stream) {
    const float* x = (const float*)d_in[0];
    float* out    = (float*)d_out;                        // Re(FFT2) : 16,777,216 floats
    float* visual = out + (size_t)BB * SS * DD;           // softmax  : 16,777,216 floats

    char* ws = (char*)d_ws;
    float2* E1   = (float2*)ws;                                  // 64 MiB: [b][k][d]
    float2* Zrow = (float2*)(ws + (size_t)BB * 1024 * 1024 * sizeof(float2));  // 64 KiB

    hipLaunchKernelGGL(k_fft_sx, dim3(BB * 64), dim3(1024), 0, stream, x, visual, E1);
    hipLaunchKernelGGL(k_fft_dd, dim3(BB * 256), dim3(256), 0, stream, E1, out, Zrow);
}